// Round 2
// baseline (10223.151 us; speedup 1.0000x reference)
//
#include <hip/hip_runtime.h>

#define B_ 32
#define S_ 64
#define T_ 64
#define H_ 512
#define E_ 256
#define V_ 32000

__device__ __forceinline__ float sigm(float x){ return 1.f/(1.f + __expf(-x)); }
__device__ __forceinline__ float ftanh(float x){
  x = fminf(fmaxf(x, -15.f), 15.f);
  float e = __expf(2.f*x);
  return (e - 1.f)/(e + 1.f);
}

__global__ __launch_bounds__(256) void zero_kernel(float* __restrict__ p, int n){
  int i = blockIdx.x*256 + threadIdx.x;
  if (i < n) p[i] = 0.f;
}

// embT[t][e][b] = tab[tgt[b][t]][e]
__global__ __launch_bounds__(256) void embed_gather(const int* __restrict__ tgt,
                                                    const float* __restrict__ tab,
                                                    float* __restrict__ embT){
  int idx = blockIdx.x*256 + threadIdx.x; // 64*256*32 = 524288
  int b = idx & 31;
  int e = (idx >> 5) & 255;
  int t = idx >> 13;
  int row = tgt[b*T_ + t];
  embT[idx] = tab[(size_t)row*E_ + e];
}

// dst[j][i] = src[i][j], 512x512
__global__ __launch_bounds__(256) void transpose512(const float* __restrict__ src,
                                                    float* __restrict__ dst){
  int idx = blockIdx.x*256 + threadIdx.x;
  int i = idx >> 9, j = idx & 511;
  dst[j*512 + i] = src[i*512 + j];
}

// kpT[b][i][s] = sum_j enc[b][s][j] * Wk[i][j]
__global__ __launch_bounds__(256) void kproj_kernel(const float* __restrict__ enc,
                                                    const float* __restrict__ Wk,
                                                    float* __restrict__ kpT){
  int i0 = blockIdx.x * 64;
  int b  = blockIdx.y;
  __shared__ float Et[32][64]; // [j][s]
  __shared__ float Wt[32][64]; // [j][i]
  int tid = threadIdx.x;
  int s  = tid >> 2, jq = tid & 3;   // loader mapping (s doubles as row idx for Wk)
  int iw = tid & 15, sw = tid >> 4;  // compute mapping
  float acc[4][4] = {};
  for (int j0 = 0; j0 < 512; j0 += 32){
    const float* ep = enc + ((size_t)(b*64 + s))*512 + j0 + jq*4;
    float4 e0 = *(const float4*)(ep);
    float4 e1 = *(const float4*)(ep + 16);
    const float* wp = Wk + ((size_t)(i0 + s))*512 + j0 + jq*4;
    float4 w0 = *(const float4*)(wp);
    float4 w1 = *(const float4*)(wp + 16);
    __syncthreads();
    Et[jq*4+0][s] = e0.x; Et[jq*4+1][s] = e0.y; Et[jq*4+2][s] = e0.z; Et[jq*4+3][s] = e0.w;
    Et[jq*4+16][s] = e1.x; Et[jq*4+17][s] = e1.y; Et[jq*4+18][s] = e1.z; Et[jq*4+19][s] = e1.w;
    Wt[jq*4+0][s] = w0.x; Wt[jq*4+1][s] = w0.y; Wt[jq*4+2][s] = w0.z; Wt[jq*4+3][s] = w0.w;
    Wt[jq*4+16][s] = w1.x; Wt[jq*4+17][s] = w1.y; Wt[jq*4+18][s] = w1.z; Wt[jq*4+19][s] = w1.w;
    __syncthreads();
    #pragma unroll
    for (int jj = 0; jj < 32; ++jj){
      float av[4], wv[4];
      *(float4*)av = *(const float4*)&Et[jj][sw*4];
      *(float4*)wv = *(const float4*)&Wt[jj][iw*4];
      #pragma unroll
      for (int a = 0; a < 4; ++a)
        #pragma unroll
        for (int c = 0; c < 4; ++c)
          acc[a][c] = fmaf(wv[a], av[c], acc[a][c]);
    }
  }
  #pragma unroll
  for (int a = 0; a < 4; ++a){
    float4 o = make_float4(acc[a][0], acc[a][1], acc[a][2], acc[a][3]);
    *(float4*)(kpT + ((size_t)(b*512 + i0 + iw*4 + a))*64 + sw*4) = o;
  }
}

// One GRU cell step. States are feature-major: xT [K][32], hT [512][32].
// Wih [1536][K1+K2], Whh [1536][512]. Writes hNewT [512][32], optionally A rows.
__global__ __launch_bounds__(256) void gru_step(
    const float* __restrict__ x1T, int K1,
    const float* __restrict__ x2T, int K2,
    const float* __restrict__ hT,
    const float* __restrict__ Wih,
    const float* __restrict__ Whh,
    const float* __restrict__ bih,
    const float* __restrict__ bhh,
    float* __restrict__ hNewT,
    float* __restrict__ Arow){
  __shared__ float Li[8][32][6];
  __shared__ float Lh[8][32][6];
  int tid = threadIdx.x;
  int b = tid & 31;
  int kp = tid >> 5;            // 8-way K split
  int j0 = blockIdx.x * 2;      // 2 hidden units per block
  int Kx = K1 + K2;
  int cx = Kx >> 3;
  float ai[2][3] = {{0.f,0.f,0.f},{0.f,0.f,0.f}};
  float ah[2][3] = {{0.f,0.f,0.f},{0.f,0.f,0.f}};
  const float* wi[2][3];
  const float* wh[2][3];
  #pragma unroll
  for (int jj = 0; jj < 2; ++jj)
    #pragma unroll
    for (int g = 0; g < 3; ++g){
      wi[jj][g] = Wih + (size_t)(g*512 + j0 + jj) * Kx;
      wh[jj][g] = Whh + (size_t)(g*512 + j0 + jj) * 512;
    }
  int ks = kp * cx, ke = ks + cx;
  #pragma unroll 4
  for (int k = ks; k < ke; ++k){
    float xv = (k < K1) ? x1T[k*32 + b] : x2T[(k - K1)*32 + b];
    #pragma unroll
    for (int jj = 0; jj < 2; ++jj)
      #pragma unroll
      for (int g = 0; g < 3; ++g)
        ai[jj][g] = fmaf(wi[jj][g][k], xv, ai[jj][g]);
  }
  int hs = kp * 64, he = hs + 64;
  #pragma unroll 4
  for (int k = hs; k < he; ++k){
    float hv = hT[k*32 + b];
    #pragma unroll
    for (int jj = 0; jj < 2; ++jj)
      #pragma unroll
      for (int g = 0; g < 3; ++g)
        ah[jj][g] = fmaf(wh[jj][g][k], hv, ah[jj][g]);
  }
  #pragma unroll
  for (int jj = 0; jj < 2; ++jj)
    #pragma unroll
    for (int g = 0; g < 3; ++g){
      Li[kp][b][jj*3+g] = ai[jj][g];
      Lh[kp][b][jj*3+g] = ah[jj][g];
    }
  __syncthreads();
  if (tid < 64){
    int bb = tid & 31, jj = tid >> 5;
    int row = j0 + jj;
    float gi[3], gh[3];
    #pragma unroll
    for (int g = 0; g < 3; ++g){
      float si = 0.f, sh = 0.f;
      #pragma unroll
      for (int p = 0; p < 8; ++p){ si += Li[p][bb][jj*3+g]; sh += Lh[p][bb][jj*3+g]; }
      gi[g] = si + bih[g*512 + row];
      gh[g] = sh + bhh[g*512 + row];
    }
    float r = sigm(gi[0] + gh[0]);
    float z = sigm(gi[1] + gh[1]);
    float n = ftanh(gi[2] + r*gh[2]);
    float hp = hT[row*32 + bb];
    float hn = (1.f - z)*n + z*hp;
    hNewT[row*32 + bb] = hn;
    if (Arow) Arow[bb*1024 + row] = hn;
  }
}

// Bahdanau attention for one step. One block per batch element, 512 threads.
__global__ __launch_bounds__(512) void attn_step(
    const float* __restrict__ h1T,   // [512][32]
    const float* __restrict__ WqT,   // [512][512] (j-major: WqT[j][i] = Wq[i][j])
    const float* __restrict__ kpT,   // [32][512][64]
    const float* __restrict__ vvec,  // [512]
    const float* __restrict__ enc,   // [32][64][512]
    const unsigned char* __restrict__ mask, // [32][64] bool
    float* __restrict__ ctxNewT,     // [512][32]
    float* __restrict__ ACtx){       // A + t*32*1024 + 512 ; index b*1024 + i
  int b = blockIdx.x;
  __shared__ float hbuf[512];
  __shared__ float qbuf[512];
  __shared__ float epart[8][64];
  __shared__ float abuf[64];
  int tid = threadIdx.x;
  hbuf[tid] = h1T[tid*32 + b];
  __syncthreads();
  // q[i] = sum_j Wq[i][j] h1[j]
  float acc = 0.f;
  #pragma unroll 4
  for (int j = 0; j < 512; ++j) acc = fmaf(WqT[j*512 + tid], hbuf[j], acc);
  qbuf[tid] = acc;
  __syncthreads();
  // e[s] = sum_i v[i] * tanh(q[i] + kp[i][s])
  int s = tid & 63, ig = tid >> 6;
  const float* kp = kpT + (size_t)b*512*64;
  float ea = 0.f;
  for (int i = ig*64; i < ig*64 + 64; ++i){
    float x = qbuf[i] + kp[i*64 + s];
    ea = fmaf(vvec[i], ftanh(x), ea);
  }
  epart[ig][s] = ea;
  __syncthreads();
  if (tid < 64){
    float e = 0.f;
    #pragma unroll
    for (int g = 0; g < 8; ++g) e += epart[g][s];
    if (mask[b*64 + s]) e = -1e9f;
    float m = e;
    #pragma unroll
    for (int off = 32; off; off >>= 1) m = fmaxf(m, __shfl_xor(m, off));
    float p = __expf(e - m);
    float sum = p;
    #pragma unroll
    for (int off = 32; off; off >>= 1) sum += __shfl_xor(sum, off);
    abuf[s] = p / sum;
  }
  __syncthreads();
  // ctx[i] = sum_s a[s] * enc[b][s][i]
  const float* encb = enc + (size_t)b*64*512;
  float c = 0.f;
  #pragma unroll 4
  for (int s2 = 0; s2 < 64; ++s2) c = fmaf(abuf[s2], encb[s2*512 + tid], c);
  ctxNewT[tid*32 + b] = c;
  ACtx[b*1024 + tid] = c;
}

// out[b][t][v] = sum_k A[t*32+b][k] * Wout[v][k] + bout[v]
// 128x128 tile, 8x8 microtile, BK=16.
__global__ __launch_bounds__(256) void logits_gemm(const float* __restrict__ A,
                                                   const float* __restrict__ W,
                                                   const float* __restrict__ bo,
                                                   float* __restrict__ out){
  __shared__ float As[16][128];
  __shared__ float Bs[16][128];
  int n0 = blockIdx.x * 128;
  int m0 = blockIdx.y * 128;
  int tid = threadIdx.x;
  int r = tid >> 2, c = (tid & 3) * 4;
  int mi = tid & 15, ni = tid >> 4;
  float acc[8][8] = {};
  for (int k0 = 0; k0 < 1024; k0 += 16){
    float4 a0 = *(const float4*)(A + (size_t)(m0 + r)*1024 + k0 + c);
    float4 a1 = *(const float4*)(A + (size_t)(m0 + r + 64)*1024 + k0 + c);
    float4 w0 = *(const float4*)(W + (size_t)(n0 + r)*1024 + k0 + c);
    float4 w1 = *(const float4*)(W + (size_t)(n0 + r + 64)*1024 + k0 + c);
    __syncthreads();
    As[c+0][r] = a0.x; As[c+1][r] = a0.y; As[c+2][r] = a0.z; As[c+3][r] = a0.w;
    As[c+0][r+64] = a1.x; As[c+1][r+64] = a1.y; As[c+2][r+64] = a1.z; As[c+3][r+64] = a1.w;
    Bs[c+0][r] = w0.x; Bs[c+1][r] = w0.y; Bs[c+2][r] = w0.z; Bs[c+3][r] = w0.w;
    Bs[c+0][r+64] = w1.x; Bs[c+1][r+64] = w1.y; Bs[c+2][r+64] = w1.z; Bs[c+3][r+64] = w1.w;
    __syncthreads();
    #pragma unroll
    for (int kk = 0; kk < 16; ++kk){
      float av[8], wv[8];
      *(float4*)(av)   = *(const float4*)&As[kk][mi*8];
      *(float4*)(av+4) = *(const float4*)&As[kk][mi*8+4];
      *(float4*)(wv)   = *(const float4*)&Bs[kk][ni*8];
      *(float4*)(wv+4) = *(const float4*)&Bs[kk][ni*8+4];
      #pragma unroll
      for (int ii = 0; ii < 8; ++ii)
        #pragma unroll
        for (int jj = 0; jj < 8; ++jj)
          acc[ii][jj] = fmaf(av[ii], wv[jj], acc[ii][jj]);
    }
  }
  float bv[8];
  #pragma unroll
  for (int jj = 0; jj < 8; ++jj) bv[jj] = bo[n0 + ni*8 + jj];
  #pragma unroll
  for (int ii = 0; ii < 8; ++ii){
    int m = m0 + mi*8 + ii;
    int bb = m & 31, t = m >> 5;
    float* orow = out + (size_t)(bb*64 + t)*32000 + n0 + ni*8;
    float4 o0 = make_float4(acc[ii][0]+bv[0], acc[ii][1]+bv[1], acc[ii][2]+bv[2], acc[ii][3]+bv[3]);
    float4 o1 = make_float4(acc[ii][4]+bv[4], acc[ii][5]+bv[5], acc[ii][6]+bv[6], acc[ii][7]+bv[7]);
    *(float4*)(orow)   = o0;
    *(float4*)(orow+4) = o1;
  }
}

extern "C" void kernel_launch(void* const* d_in, const int* in_sizes, int n_in,
                              void* d_out, int out_size, void* d_ws, size_t ws_size,
                              hipStream_t stream){
  const float* enc  = (const float*)d_in[0];
  const unsigned char* mask = (const unsigned char*)d_in[1];
  const int*   tgt  = (const int*)d_in[2];
  const float* tab  = (const float*)d_in[3];
  const float* Wih0 = (const float*)d_in[4];
  const float* Whh0 = (const float*)d_in[5];
  const float* bih0 = (const float*)d_in[6];
  const float* bhh0 = (const float*)d_in[7];
  const float* Wih1 = (const float*)d_in[8];
  const float* Whh1 = (const float*)d_in[9];
  const float* bih1 = (const float*)d_in[10];
  const float* bhh1 = (const float*)d_in[11];
  const float* Wq   = (const float*)d_in[12];
  const float* Wk   = (const float*)d_in[13];
  const float* vv   = (const float*)d_in[14];
  const float* Wout = (const float*)d_in[15];
  const float* bout = (const float*)d_in[16];
  float* out = (float*)d_out;
  float* ws  = (float*)d_ws;

  const int ST = H_*B_; // 16384 floats per state buffer
  float* stateA = ws;           // [h0 | h1 | ctx]
  float* stateB = ws + 3*ST;
  float* embT   = ws + 6*ST;               // 64*256*32
  float* kpT    = embT + T_*E_*B_;         // 32*512*64
  float* WqT    = kpT + (size_t)B_*H_*S_;  // 512*512
  float* Amat   = WqT + H_*H_;             // 2048*1024

  zero_kernel<<<(3*ST + 255)/256, 256, 0, stream>>>(stateA, 3*ST);
  embed_gather<<<(T_*E_*B_)/256, 256, 0, stream>>>(tgt, tab, embT);
  transpose512<<<(H_*H_)/256, 256, 0, stream>>>(Wq, WqT);
  kproj_kernel<<<dim3(8, 32), 256, 0, stream>>>(enc, Wk, kpT);

  for (int t = 0; t < 64; ++t){
    float* cur = (t & 1) ? stateB : stateA;
    float* nxt = (t & 1) ? stateA : stateB;
    float* h0c = cur,        *h1c = cur + ST, *cxc = cur + 2*ST;
    float* h0n = nxt,        *h1n = nxt + ST, *cxn = nxt + 2*ST;
    float* Arow = Amat + (size_t)t*32*1024;
    // layer 0: x = [emb_t (256), ctx (512)]
    gru_step<<<256, 256, 0, stream>>>(embT + (size_t)t*E_*B_, E_, cxc, H_, h0c,
                                      Wih0, Whh0, bih0, bhh0, h0n, nullptr);
    // layer 1: x = h0_new (512). x2 pointer unused (K2=0) but kept valid.
    gru_step<<<256, 256, 0, stream>>>(h0n, H_, h1c, 0, h1c,
                                      Wih1, Whh1, bih1, bhh1, h1n, Arow);
    attn_step<<<32, 512, 0, stream>>>(h1n, WqT, kpT, vv, enc, mask, cxn, Arow + 512);
  }
  logits_gemm<<<dim3(250, 16), 256, 0, stream>>>(Amat, Wout, bout, out);
}

// Round 4
// 7651.785 us; speedup vs baseline: 1.3360x; 1.3360x over previous
//
#include <hip/hip_runtime.h>

#define B_ 32
#define S_ 64
#define T_ 64
#define H_ 512
#define E_ 256
#define V_ 32000
#define NWG 128

// workspace float offsets
#define OFF_STATE 0            // 6 * 16384 (h0[2], h1[2], ctx[2], feature-major [512][32])
#define OFF_QG    98304        // q [32][512]
#define OFF_BAR   114688       // barrier ints (32 floats reserved)
#define OFF_EMBT  114720       // [64][256][32]
#define OFF_KPT   639008       // [32][512][64]
#define OFF_AMAT  1687584      // [2048][1024]
#define ZERO_N    114720
#define LDS_FLOATS (12*772 + 3*12*516 + 6144)

__device__ __forceinline__ float sigm(float x){ return 1.f/(1.f + __expf(-x)); }
__device__ __forceinline__ float ftanh(float x){
  x = fminf(fmaxf(x, -15.f), 15.f);
  float e = __expf(2.f*x);
  return (e - 1.f)/(e + 1.f);
}

__global__ __launch_bounds__(256) void init_state(float* __restrict__ ws){
  int i = blockIdx.x*256 + threadIdx.x;
  if (i < ZERO_N) ws[i] = 0.f;
}

// embT[t][e][b] = tab[tgt[b][t]][e]
__global__ __launch_bounds__(256) void embed_gather(const int* __restrict__ tgt,
                                                    const float* __restrict__ tab,
                                                    float* __restrict__ embT){
  int idx = blockIdx.x*256 + threadIdx.x;
  int b = idx & 31;
  int e = (idx >> 5) & 255;
  int t = idx >> 13;
  int row = tgt[b*T_ + t];
  embT[idx] = tab[(size_t)row*E_ + e];
}

// kpT[b][i][s] = sum_j enc[b][s][j] * Wk[i][j]
__global__ __launch_bounds__(256) void kproj_kernel(const float* __restrict__ enc,
                                                    const float* __restrict__ Wk,
                                                    float* __restrict__ kpT){
  int i0 = blockIdx.x * 64;
  int b  = blockIdx.y;
  __shared__ float Et[32][64];
  __shared__ float Wt[32][64];
  int tid = threadIdx.x;
  int s  = tid >> 2, jq = tid & 3;
  int iw = tid & 15, sw = tid >> 4;
  float acc[4][4] = {};
  for (int j0 = 0; j0 < 512; j0 += 32){
    const float* ep = enc + ((size_t)(b*64 + s))*512 + j0 + jq*4;
    float4 e0 = *(const float4*)(ep);
    float4 e1 = *(const float4*)(ep + 16);
    const float* wp = Wk + ((size_t)(i0 + s))*512 + j0 + jq*4;
    float4 w0 = *(const float4*)(wp);
    float4 w1 = *(const float4*)(wp + 16);
    __syncthreads();
    Et[jq*4+0][s] = e0.x; Et[jq*4+1][s] = e0.y; Et[jq*4+2][s] = e0.z; Et[jq*4+3][s] = e0.w;
    Et[jq*4+16][s] = e1.x; Et[jq*4+17][s] = e1.y; Et[jq*4+18][s] = e1.z; Et[jq*4+19][s] = e1.w;
    Wt[jq*4+0][s] = w0.x; Wt[jq*4+1][s] = w0.y; Wt[jq*4+2][s] = w0.z; Wt[jq*4+3][s] = w0.w;
    Wt[jq*4+16][s] = w1.x; Wt[jq*4+17][s] = w1.y; Wt[jq*4+18][s] = w1.z; Wt[jq*4+19][s] = w1.w;
    __syncthreads();
    #pragma unroll
    for (int jj = 0; jj < 32; ++jj){
      float av[4], wv[4];
      *(float4*)av = *(const float4*)&Et[jj][sw*4];
      *(float4*)wv = *(const float4*)&Wt[jj][iw*4];
      #pragma unroll
      for (int a = 0; a < 4; ++a)
        #pragma unroll
        for (int c = 0; c < 4; ++c)
          acc[a][c] = fmaf(wv[a], av[c], acc[a][c]);
    }
  }
  #pragma unroll
  for (int a = 0; a < 4; ++a){
    float4 o = make_float4(acc[a][0], acc[a][1], acc[a][2], acc[a][3]);
    *(float4*)(kpT + ((size_t)(b*512 + i0 + iw*4 + a))*64 + sw*4) = o;
  }
}

__device__ __forceinline__ void accum4(float (&a)[3][4], const float* Wp, int wstr,
                                       const float* __restrict__ xv){
  float4 xk0 = *(const float4*)(xv);
  float4 xk1 = *(const float4*)(xv + 32);
  float4 xk2 = *(const float4*)(xv + 64);
  float4 xk3 = *(const float4*)(xv + 96);
  #pragma unroll
  for (int g = 0; g < 3; ++g){
    float4 w = *(const float4*)(Wp + g*wstr);
    a[g][0] = fmaf(w.x, xk0.x, a[g][0]);
    a[g][1] = fmaf(w.x, xk0.y, a[g][1]);
    a[g][2] = fmaf(w.x, xk0.z, a[g][2]);
    a[g][3] = fmaf(w.x, xk0.w, a[g][3]);
    a[g][0] = fmaf(w.y, xk1.x, a[g][0]);
    a[g][1] = fmaf(w.y, xk1.y, a[g][1]);
    a[g][2] = fmaf(w.y, xk1.z, a[g][2]);
    a[g][3] = fmaf(w.y, xk1.w, a[g][3]);
    a[g][0] = fmaf(w.z, xk2.x, a[g][0]);
    a[g][1] = fmaf(w.z, xk2.y, a[g][1]);
    a[g][2] = fmaf(w.z, xk2.z, a[g][2]);
    a[g][3] = fmaf(w.z, xk2.w, a[g][3]);
    a[g][0] = fmaf(w.w, xk3.x, a[g][0]);
    a[g][1] = fmaf(w.w, xk3.y, a[g][1]);
    a[g][2] = fmaf(w.w, xk3.z, a[g][2]);
    a[g][3] = fmaf(w.w, xk3.w, a[g][3]);
  }
}

// One GRU layer phase for 4 units owned by this WG.
__device__ __forceinline__ void gru_phase(int tid, int wg,
    const float* __restrict__ x1, int K1,
    const float* __restrict__ x2, int K2,
    const float* __restrict__ hprev,
    const float* Wi, int wstr, const float* Wh,
    const float* __restrict__ bi, const float* __restrict__ bh,
    float* Sc, float* __restrict__ hNew, float* __restrict__ Arow)
{
  int bq = tid & 7, uu = (tid >> 3) & 3, kp = tid >> 5;
  int Kx = K1 + K2, ck = Kx >> 3;
  float ai[3][4] = {{0,0,0,0},{0,0,0,0},{0,0,0,0}};
  float ah[3][4] = {{0,0,0,0},{0,0,0,0},{0,0,0,0}};
  int ks = kp*ck, ke = ks + ck;
  int e1 = ke < K1 ? ke : K1;
  for (int k = ks; k < e1; k += 4)
    accum4(ai, Wi + (uu*3)*wstr + k, wstr, x1 + k*32 + bq*4);
  int s2 = ks > K1 ? ks : K1;
  for (int k = s2; k < ke; k += 4)
    accum4(ai, Wi + (uu*3)*wstr + k, wstr, x2 + (k - K1)*32 + bq*4);
  int hs = kp*64;
  for (int k = hs; k < hs + 64; k += 4)
    accum4(ah, Wh + (uu*3)*516 + k, 516, hprev + k*32 + bq*4);
  #pragma unroll
  for (int g = 0; g < 3; ++g){
    *(float4*)&Sc[(((g    )*4 + uu)*8 + kp)*32 + bq*4] = *(float4*)ai[g];
    *(float4*)&Sc[(((g + 3)*4 + uu)*8 + kp)*32 + bq*4] = *(float4*)ah[g];
  }
  __syncthreads();
  if (tid < 128){
    int b = tid & 31, u = tid >> 5;
    int j = wg*4 + u;
    float s[6];
    #pragma unroll
    for (int g = 0; g < 6; ++g){
      float acc = 0.f;
      #pragma unroll
      for (int p2 = 0; p2 < 8; ++p2) acc += Sc[((g*4 + u)*8 + p2)*32 + b];
      s[g] = acc;
    }
    float r = sigm(s[0] + bi[j]       + s[3] + bh[j]);
    float z = sigm(s[1] + bi[512+j]   + s[4] + bh[512+j]);
    float n = ftanh(s[2] + bi[1024+j] + r*(s[5] + bh[1024+j]));
    float hp = hprev[j*32 + b];
    float hn = (1.f - z)*n + z*hp;
    hNew[j*32 + b] = hn;
    if (Arow) Arow[b*1024 + j] = hn;
  }
}

__global__ __launch_bounds__(256, 1) void decoder_persistent(
    const float* __restrict__ emb,
    const float* __restrict__ enc,
    const unsigned char* __restrict__ mask,
    const float* __restrict__ Wih0, const float* __restrict__ Whh0,
    const float* __restrict__ bih0, const float* __restrict__ bhh0,
    const float* __restrict__ Wih1, const float* __restrict__ Whh1,
    const float* __restrict__ bih1, const float* __restrict__ bhh1,
    const float* __restrict__ Wq, const float* __restrict__ vvec,
    const float* __restrict__ kpT,
    float* __restrict__ states, float* __restrict__ qg,
    float* __restrict__ Amat, int* bar)
{
  extern __shared__ float lds[];
  float* Wi0 = lds;                 // [12][772]
  float* Wh0 = Wi0 + 12*772;        // [12][516]
  float* Wi1 = Wh0 + 12*516;        // [12][516]
  float* Wh1 = Wi1 + 12*516;        // [12][516]
  float* Sc  = Wh1 + 12*516;        // 6144 floats scratch
  int tid = threadIdx.x;
  int wg = blockIdx.x;

  // ---- load this WG's weight slices into LDS (once) ----
  for (int r = 0; r < 12; ++r){
    int uu = r/3, g = r%3, j = wg*4 + uu;
    if (tid < 192)
      *(float4*)(Wi0 + r*772 + tid*4) = *(const float4*)(Wih0 + ((size_t)(g*512 + j))*768 + tid*4);
    if (tid < 128){
      *(float4*)(Wh0 + r*516 + tid*4) = *(const float4*)(Whh0 + ((size_t)(g*512 + j))*512 + tid*4);
      *(float4*)(Wi1 + r*516 + tid*4) = *(const float4*)(Wih1 + ((size_t)(g*512 + j))*512 + tid*4);
      *(float4*)(Wh1 + r*516 + tid*4) = *(const float4*)(Whh1 + ((size_t)(g*512 + j))*512 + tid*4);
    }
  }
  __syncthreads();

  float* h0[2] = { states,          states + 16384 };
  float* h1[2] = { states + 32768,  states + 49152 };
  float* cx[2] = { states + 65536,  states + 81920 };
  int* cnt = bar; int* flg = bar + 1;
  bool dead = false;

  auto gbar = [&](){
    __syncthreads();
    if (tid == 0 && !dead){
      __builtin_amdgcn_fence(__ATOMIC_RELEASE, "agent");
      int g = __hip_atomic_load(flg, __ATOMIC_RELAXED, __HIP_MEMORY_SCOPE_AGENT);
      int a = __hip_atomic_fetch_add(cnt, 1, __ATOMIC_RELAXED, __HIP_MEMORY_SCOPE_AGENT);
      if (a == NWG - 1){
        __hip_atomic_store(cnt, 0, __ATOMIC_RELAXED, __HIP_MEMORY_SCOPE_AGENT);
        __hip_atomic_store(flg, g + 1, __ATOMIC_RELEASE, __HIP_MEMORY_SCOPE_AGENT);
      } else {
        int sp = 0;
        while (__hip_atomic_load(flg, __ATOMIC_RELAXED, __HIP_MEMORY_SCOPE_AGENT) == g){
          __builtin_amdgcn_s_sleep(1);
          if (++sp > (1 << 22)){ dead = true; break; }
        }
      }
      __builtin_amdgcn_fence(__ATOMIC_ACQUIRE, "agent");
    }
    __syncthreads();
  };

  for (int t = 0; t < 64; ++t){
    int p = t & 1;
    float* Arow = Amat + (size_t)t*32*1024;

    // P1: GRU layer 0, x = [emb_t (256) | ctx (512)]
    gru_phase(tid, wg, emb + (size_t)t*8192, 256, cx[p], 512, h0[p],
              Wi0, 772, Wh0, bih0, bhh0, Sc, h0[p^1], nullptr);
    gbar();

    // P2: GRU layer 1, x = h0_new (512); write dec into A
    gru_phase(tid, wg, h0[p^1], 512, nullptr, 0, h1[p],
              Wi1, 516, Wh1, bih1, bhh1, Sc, h1[p^1], Arow);
    gbar();

    // P3: q rows for this WG: q[b][i] = sum_j Wq[i][j] * h1n[j][b]
    {
      int bq = tid & 7, uu = (tid >> 3) & 3, kp = tid >> 5;
      float aq[4] = {0,0,0,0};
      const float* wrow = Wq + ((size_t)(wg*4 + uu))*512;
      const float* h1n = h1[p^1];
      int ks = kp*64;
      for (int k = ks; k < ks + 64; k += 4){
        float4 w = *(const float4*)(wrow + k);
        const float* xv = h1n + k*32 + bq*4;
        float4 x0 = *(const float4*)(xv);
        float4 x1 = *(const float4*)(xv + 32);
        float4 x2 = *(const float4*)(xv + 64);
        float4 x3 = *(const float4*)(xv + 96);
        aq[0] = fmaf(w.x, x0.x, aq[0]); aq[1] = fmaf(w.x, x0.y, aq[1]);
        aq[2] = fmaf(w.x, x0.z, aq[2]); aq[3] = fmaf(w.x, x0.w, aq[3]);
        aq[0] = fmaf(w.y, x1.x, aq[0]); aq[1] = fmaf(w.y, x1.y, aq[1]);
        aq[2] = fmaf(w.y, x1.z, aq[2]); aq[3] = fmaf(w.y, x1.w, aq[3]);
        aq[0] = fmaf(w.z, x2.x, aq[0]); aq[1] = fmaf(w.z, x2.y, aq[1]);
        aq[2] = fmaf(w.z, x2.z, aq[2]); aq[3] = fmaf(w.z, x2.w, aq[3]);
        aq[0] = fmaf(w.w, x3.x, aq[0]); aq[1] = fmaf(w.w, x3.y, aq[1]);
        aq[2] = fmaf(w.w, x3.z, aq[2]); aq[3] = fmaf(w.w, x3.w, aq[3]);
      }
      *(float4*)&Sc[(uu*8 + kp)*32 + bq*4] = *(float4*)aq;
      __syncthreads();
      if (tid < 128){
        int b = tid & 31, u = tid >> 5;
        float acc = 0.f;
        #pragma unroll
        for (int p2 = 0; p2 < 8; ++p2) acc += Sc[((u*8 + p2)*32) + b];
        qg[b*512 + wg*4 + u] = acc;
      }
    }
    gbar();

    // P4: attention for b = wg (first 32 WGs)
    if (wg < 32){
      int b = wg;
      float* qs = Sc; float* vs = Sc + 512; float* ep = Sc + 1024; float* abuf = Sc + 1280;
      qs[tid]       = qg[b*512 + tid];
      qs[tid + 256] = qg[b*512 + tid + 256];
      vs[tid]       = vvec[tid];
      vs[tid + 256] = vvec[tid + 256];
      __syncthreads();
      int s = tid & 63, iq = tid >> 6;
      const float* kpb = kpT + ((size_t)b*512 + iq*128)*64 + s;
      const float* qq = qs + iq*128;
      const float* vq = vs + iq*128;
      float ea = 0.f;
      #pragma unroll 4
      for (int ii = 0; ii < 128; ++ii)
        ea = fmaf(vq[ii], ftanh(qq[ii] + kpb[ii*64]), ea);
      ep[iq*64 + s] = ea;
      __syncthreads();
      if (tid < 64){
        float e = ep[s] + ep[64 + s] + ep[128 + s] + ep[192 + s];
        if (mask[b*64 + s]) e = -1e9f;
        float m = e;
        #pragma unroll
        for (int off = 32; off; off >>= 1) m = fmaxf(m, __shfl_xor(m, off));
        float pp = __expf(e - m);
        float ss = pp;
        #pragma unroll
        for (int off = 32; off; off >>= 1) ss += __shfl_xor(ss, off);
        abuf[s] = pp / ss;
      }
      __syncthreads();
      float c0 = 0.f, c1 = 0.f;
      const float* encb = enc + (size_t)b*64*512;
      #pragma unroll 4
      for (int s2 = 0; s2 < 64; ++s2){
        float a = abuf[s2];
        c0 = fmaf(a, encb[s2*512 + tid], c0);
        c1 = fmaf(a, encb[s2*512 + tid + 256], c1);
      }
      float* cxn = cx[p^1];
      cxn[tid*32 + b] = c0;
      cxn[(tid + 256)*32 + b] = c1;
      Arow[b*1024 + 512 + tid] = c0;
      Arow[b*1024 + 512 + tid + 256] = c1;
    }
    gbar();
  }
}

// out[b][t][v] = sum_k A[t*32+b][k] * Wout[v][k] + bout[v]
// grid: x = m-tiles (16), y = n-tiles (250) so consecutive blocks share a W-tile.
__global__ __launch_bounds__(256) void logits_gemm(const float* __restrict__ A,
                                                   const float* __restrict__ W,
                                                   const float* __restrict__ bo,
                                                   float* __restrict__ out){
  __shared__ float As[16][128];
  __shared__ float Bs[16][128];
  int m0 = blockIdx.x * 128;
  int n0 = blockIdx.y * 128;
  int tid = threadIdx.x;
  int r = tid >> 2, c = (tid & 3) * 4;
  int mi = tid & 15, ni = tid >> 4;
  float acc[8][8] = {};
  for (int k0 = 0; k0 < 1024; k0 += 16){
    float4 a0 = *(const float4*)(A + (size_t)(m0 + r)*1024 + k0 + c);
    float4 a1 = *(const float4*)(A + (size_t)(m0 + r + 64)*1024 + k0 + c);
    float4 w0 = *(const float4*)(W + (size_t)(n0 + r)*1024 + k0 + c);
    float4 w1 = *(const float4*)(W + (size_t)(n0 + r + 64)*1024 + k0 + c);
    __syncthreads();
    As[c+0][r] = a0.x; As[c+1][r] = a0.y; As[c+2][r] = a0.z; As[c+3][r] = a0.w;
    As[c+0][r+64] = a1.x; As[c+1][r+64] = a1.y; As[c+2][r+64] = a1.z; As[c+3][r+64] = a1.w;
    Bs[c+0][r] = w0.x; Bs[c+1][r] = w0.y; Bs[c+2][r] = w0.z; Bs[c+3][r] = w0.w;
    Bs[c+0][r+64] = w1.x; Bs[c+1][r+64] = w1.y; Bs[c+2][r+64] = w1.z; Bs[c+3][r+64] = w1.w;
    __syncthreads();
    #pragma unroll
    for (int kk = 0; kk < 16; ++kk){
      float av[8], wv[8];
      #pragma unroll
      for (int q = 0; q < 4; ++q){
        float2 a2 = *(const float2*)&As[kk][mi*2 + 32*q];
        av[q*2]   = a2.x;
        av[q*2+1] = a2.y;
      }
      *(float4*)(wv)     = *(const float4*)&Bs[kk][ni*8];
      *(float4*)(wv + 4) = *(const float4*)&Bs[kk][ni*8 + 4];
      #pragma unroll
      for (int ii = 0; ii < 8; ++ii)
        #pragma unroll
        for (int jj = 0; jj < 8; ++jj)
          acc[ii][jj] = fmaf(av[ii], wv[jj], acc[ii][jj]);
    }
  }
  float bv[8];
  #pragma unroll
  for (int jj = 0; jj < 8; ++jj) bv[jj] = bo[n0 + ni*8 + jj];
  #pragma unroll
  for (int q = 0; q < 4; ++q)
    #pragma unroll
    for (int jr = 0; jr < 2; ++jr){
      int ii = q*2 + jr;
      int m = m0 + mi*2 + q*32 + jr;
      int bb = m & 31, tt = m >> 5;
      float* orow = out + (size_t)(bb*64 + tt)*32000 + n0 + ni*8;
      float4 o0 = make_float4(acc[ii][0]+bv[0], acc[ii][1]+bv[1], acc[ii][2]+bv[2], acc[ii][3]+bv[3]);
      float4 o1 = make_float4(acc[ii][4]+bv[4], acc[ii][5]+bv[5], acc[ii][6]+bv[6], acc[ii][7]+bv[7]);
      *(float4*)(orow)     = o0;
      *(float4*)(orow + 4) = o1;
    }
}

extern "C" void kernel_launch(void* const* d_in, const int* in_sizes, int n_in,
                              void* d_out, int out_size, void* d_ws, size_t ws_size,
                              hipStream_t stream){
  const float* enc  = (const float*)d_in[0];
  const unsigned char* mask = (const unsigned char*)d_in[1];
  const int*   tgt  = (const int*)d_in[2];
  const float* tab  = (const float*)d_in[3];
  const float* Wih0 = (const float*)d_in[4];
  const float* Whh0 = (const float*)d_in[5];
  const float* bih0 = (const float*)d_in[6];
  const float* bhh0 = (const float*)d_in[7];
  const float* Wih1 = (const float*)d_in[8];
  const float* Whh1 = (const float*)d_in[9];
  const float* bih1 = (const float*)d_in[10];
  const float* bhh1 = (const float*)d_in[11];
  const float* Wq   = (const float*)d_in[12];
  const float* Wk   = (const float*)d_in[13];
  const float* vv   = (const float*)d_in[14];
  const float* Wout = (const float*)d_in[15];
  const float* bout = (const float*)d_in[16];
  float* out = (float*)d_out;
  float* ws  = (float*)d_ws;

  (void)hipFuncSetAttribute((const void*)decoder_persistent,
                            hipFuncAttributeMaxDynamicSharedMemorySize,
                            LDS_FLOATS * 4);

  init_state<<<(ZERO_N + 255)/256, 256, 0, stream>>>(ws);
  embed_gather<<<(T_*E_*B_)/256, 256, 0, stream>>>(tgt, tab, ws + OFF_EMBT);
  kproj_kernel<<<dim3(8, 32), 256, 0, stream>>>(enc, Wk, ws + OFF_KPT);

  decoder_persistent<<<NWG, 256, LDS_FLOATS*4, stream>>>(
      ws + OFF_EMBT, enc, mask,
      Wih0, Whh0, bih0, bhh0,
      Wih1, Whh1, bih1, bhh1,
      Wq, vv, ws + OFF_KPT,
      ws + OFF_STATE, ws + OFF_QG,
      ws + OFF_AMAT, (int*)(ws + OFF_BAR));

  logits_gemm<<<dim3(16, 250), 256, 0, stream>>>(ws + OFF_AMAT, Wout, bout, out);
}